// Round 5
// baseline (1252.649 us; speedup 1.0000x reference)
//
#include <hip/hip_runtime.h>

#define B_ 128
#define T_ 1024
#define D_ 128
#define H_ 128

typedef short bf16x8 __attribute__((ext_vector_type(8)));
typedef float f32x4 __attribute__((ext_vector_type(4)));

// pack 2 f32 -> 2 bf16 (RNE) in one instruction (no builtin on gfx950)
__device__ inline unsigned cvt_pk_bf16(float lo, float hi) {
    unsigned r;
    asm("v_cvt_pk_bf16_f32 %0, %1, %2" : "=v"(r) : "v"(lo), "v"(hi));
    return r;
}

// tanh(x) = 1 - 2/(1+2^(x*2*log2(e))): mul, v_exp, add, rcp, fma
__device__ inline float fast_tanh(float x) {
    float e = __builtin_amdgcn_exp2f(x * 2.885390081777927f);
    float r = __builtin_amdgcn_rcpf(1.0f + e);
    return fmaf(-2.0f, r, 1.0f);
}

// lgkm-only barrier: keeps in-flight global loads/stores off the critical path
__device__ inline void lds_barrier() {
    asm volatile("s_waitcnt lgkmcnt(0)\n\ts_barrier" ::: "memory");
}

// ---------------------------------------------------------------------------
// Kernel 1: xu[rid = b*T + t][h] = x_row @ U + (bu + bw)  -> out (f32).
// ---------------------------------------------------------------------------
__global__ __launch_bounds__(256) void xu_kernel(
    const float* __restrict__ x, const float* __restrict__ U,
    const float* __restrict__ bu, const float* __restrict__ bw,
    float* __restrict__ out)
{
    __shared__ bf16x8 uf[2048];  // [nt(8)][kk(4)][lane(64)]: U[k][16nt+(l&15)]
    const int tid  = threadIdx.x;
    const int lane = tid & 63;
    const int wave = tid >> 6;
    const int q = lane >> 4, c = lane & 15;

    for (int s = tid; s < 2048; s += 256) {
        int l = s & 63, kk = (s >> 6) & 3, nt = s >> 8;
        int lq = l >> 4, lc = l & 15;
        int kbase = 32 * kk + 8 * lq;
        int col = 16 * nt + lc;
        float v[8];
#pragma unroll
        for (int j = 0; j < 8; ++j) v[j] = U[(kbase + j) * H_ + col];
        union { bf16x8 v8; unsigned u[4]; } f;
#pragma unroll
        for (int j = 0; j < 4; ++j) f.u[j] = cvt_pk_bf16(v[2 * j], v[2 * j + 1]);
        uf[s] = f.v8;
    }

    f32x4 bias4[8];
#pragma unroll
    for (int nt = 0; nt < 8; ++nt) {
        const int cb = 16 * nt + 4 * q;
        f32x4 a = *(const f32x4*)(bu + cb);
        f32x4 b = *(const f32x4*)(bw + cb);
#pragma unroll
        for (int r = 0; r < 4; ++r) bias4[nt][r] = a[r] + b[r];
    }

    __syncthreads();

    for (int it = 0; it < 4; ++it) {
        const int row0 = (blockIdx.x * 4 + it) * 64 + wave * 16;
        bf16x8 af[4];
#pragma unroll
        for (int kk = 0; kk < 4; ++kk) {
            const float* px = x + (size_t)(row0 + c) * D_ + 32 * kk + 8 * q;
            f32x4 a0 = *(const f32x4*)px;
            f32x4 a1 = *(const f32x4*)(px + 4);
            union { bf16x8 v8; unsigned u[4]; } f;
            f.u[0] = cvt_pk_bf16(a0[0], a0[1]);
            f.u[1] = cvt_pk_bf16(a0[2], a0[3]);
            f.u[2] = cvt_pk_bf16(a1[0], a1[1]);
            f.u[3] = cvt_pk_bf16(a1[2], a1[3]);
            af[kk] = f.v8;
        }
        float* po = out + (size_t)(row0 + c) * H_ + 4 * q;
#pragma unroll
        for (int nt = 0; nt < 8; ++nt) {
            f32x4 acc = bias4[nt];
#pragma unroll
            for (int kk = 0; kk < 4; ++kk)
                acc = __builtin_amdgcn_mfma_f32_16x16x32_bf16(
                    uf[(nt * 4 + kk) * 64 + lane], af[kk], acc, 0, 0, 0);
            *(f32x4*)(po + 16 * nt) = acc;
        }
    }
}

// ---------------------------------------------------------------------------
// Kernel 2: serial recurrence, TWO independent 16-row batch groups per block
// (4 blocks x 256 thr, 4 waves). The two groups' dependency chains interleave
// inside each barrier window so MFMA/LDS/trans latencies of one chain are
// hidden by issue work of the other. pkg double-buffered (store reads buf A
// while compute writes buf B -> no per-step wait for store completion).
// All per-step addresses are compile-time immediates; pointers bump once per
// 8-step unroll block.
// ---------------------------------------------------------------------------
__global__ __launch_bounds__(256, 1) void scan_kernel(
    const float* __restrict__ xu_in, float* __restrict__ st_out,
    const float* __restrict__ h0, const float* __restrict__ W)
{
    // st slots: [group][parity][m=16][k=128 + 8 pad] bf16 (272B row stride)
    __shared__ __align__(16) short st[2][2][16][136];

    const int tid  = threadIdx.x;
    const int lane = tid & 63;
    const int wave = tid >> 6;           // 0..3
    const int q = lane >> 4, c = lane & 15;
    const int b0 = blockIdx.x * 32;      // 32 batch rows per block (2 groups)
    const int cw = wave * 32 + 4 * q;    // per-lane col base (tile 0)

    // A-frags of W^T (regs, all steps): A[i=lane&15][k] = W[k][c0+i]
    bf16x8 wf[2][4];
#pragma unroll
    for (int tt = 0; tt < 2; ++tt) {
        const int c0 = wave * 32 + tt * 16;
#pragma unroll
        for (int kk = 0; kk < 4; ++kk) {
            const int kbase = 32 * kk + 8 * q;
            float v[8];
#pragma unroll
            for (int j = 0; j < 8; ++j) v[j] = W[(kbase + j) * H_ + c0 + c];
            union { bf16x8 v8; unsigned u[4]; } f;
#pragma unroll
            for (int j = 0; j < 4; ++j) f.u[j] = cvt_pk_bf16(v[2 * j], v[2 * j + 1]);
            wf[tt][kk] = f.v8;
        }
    }

    // stage h0 -> slot[g][1] (st_{-1}) for both groups
    {
        const int m = tid >> 4, k0 = (tid & 15) * 8;
#pragma unroll
        for (int g = 0; g < 2; ++g) {
            const float* ph = h0 + (size_t)(b0 + 16 * g + m) * H_ + k0;
            f32x4 a0 = *(const f32x4*)ph;
            f32x4 a1 = *(const f32x4*)(ph + 4);
            union { bf16x8 v8; unsigned u[4]; } f;
            f.u[0] = cvt_pk_bf16(a0[0], a0[1]);
            f.u[1] = cvt_pk_bf16(a0[2], a0[3]);
            f.u[2] = cvt_pk_bf16(a1[0], a1[1]);
            f.u[3] = cvt_pk_bf16(a1[2], a1[3]);
            *(bf16x8*)&st[g][1][m][k0] = f.v8;
        }
    }

    // 4-deep xu FIFO per group; pfb[g] -> refill base (row t=4), psb[g] ->
    // store base (row t=0). Bumped +4096B once per 8-step unroll block.
    f32x4 xub[2][4][2];
    const char* pfb[2];
    char* psb[2];
#pragma unroll
    for (int g = 0; g < 2; ++g) {
        const float* xup = xu_in + ((size_t)(b0 + 16 * g + c) * T_) * H_ + cw;
#pragma unroll
        for (int u = 0; u < 4; ++u) {
            xub[g][u][0] = *(const f32x4*)(xup + u * H_);
            xub[g][u][1] = *(const f32x4*)(xup + u * H_ + 16);
        }
        pfb[g] = (const char*)(xup + 4 * H_);
        psb[g] = (char*)st_out + ((size_t)(b0 + 16 * g + c) * T_) * H_ * 4 + cw * 2;
    }

    // st_t packed-store state, double-buffered: pkg[group][half][buf]
    uint2 pkg[2][2][2];

    const f32x4 z4 = {0.f, 0.f, 0.f, 0.f};

    lds_barrier();

    for (int tb = 0; tb < T_ / 8; ++tb) {
#pragma unroll
        for (int u = 0; u < 8; ++u) {
            const int t = tb * 8 + u;
            const int pr = (u + 1) & 1;  // slot holding st_{t-1}
            const int pw = u & 1;        // slot to write st_t
            const int pb = (u + 1) & 1;  // pkg buffer to store (computed t-1)
            const int pc = u & 1;        // pkg buffer to compute (t)

            // A) ds_read B-frags for both groups first (longest latency)
            bf16x8 af[2][4];
#pragma unroll
            for (int g = 0; g < 2; ++g)
#pragma unroll
                for (int kk = 0; kk < 4; ++kk)
                    af[g][kk] = *(const bf16x8*)&st[g][pr][c][32 * kk + 8 * q];

            // B) store st_{t-1} (pkg buffer pb; imm offset (u-1)*512)
            if (t > 0) {
#pragma unroll
                for (int g = 0; g < 2; ++g) {
                    *(uint2*)(psb[g] + (u - 1) * 512)      = pkg[g][0][pb];
                    *(uint2*)(psb[g] + (u - 1) * 512 + 32) = pkg[g][1][pb];
                }
            }

            // C) capture current xu, then refill FIFO slot with plane t+4
            f32x4 xuc[2][2];
#pragma unroll
            for (int g = 0; g < 2; ++g) {
                xuc[g][0] = xub[g][u & 3][0];
                xuc[g][1] = xub[g][u & 3][1];
            }
            if (t + 4 < T_) {
#pragma unroll
                for (int g = 0; g < 2; ++g) {
                    xub[g][u & 3][0] = *(const f32x4*)(pfb[g] + u * 512);
                    xub[g][u & 3][1] = *(const f32x4*)(pfb[g] + u * 512 + 64);
                }
            }

            // D/E/F) per group: MFMA -> tanh -> pack -> ds_write
#pragma unroll
            for (int g = 0; g < 2; ++g) {
                f32x4 aA = __builtin_amdgcn_mfma_f32_16x16x32_bf16(wf[0][0], af[g][0], xuc[g][0], 0, 0, 0);
                f32x4 aB = __builtin_amdgcn_mfma_f32_16x16x32_bf16(wf[0][1], af[g][1], z4,       0, 0, 0);
                f32x4 bA = __builtin_amdgcn_mfma_f32_16x16x32_bf16(wf[1][0], af[g][0], xuc[g][1], 0, 0, 0);
                f32x4 bB = __builtin_amdgcn_mfma_f32_16x16x32_bf16(wf[1][1], af[g][1], z4,       0, 0, 0);
                aA = __builtin_amdgcn_mfma_f32_16x16x32_bf16(wf[0][2], af[g][2], aA, 0, 0, 0);
                aB = __builtin_amdgcn_mfma_f32_16x16x32_bf16(wf[0][3], af[g][3], aB, 0, 0, 0);
                bA = __builtin_amdgcn_mfma_f32_16x16x32_bf16(wf[1][2], af[g][2], bA, 0, 0, 0);
                bB = __builtin_amdgcn_mfma_f32_16x16x32_bf16(wf[1][3], af[g][3], bB, 0, 0, 0);

                float s0 = fast_tanh(aA[0] + aB[0]);
                float s1 = fast_tanh(aA[1] + aB[1]);
                float s2 = fast_tanh(aA[2] + aB[2]);
                float s3 = fast_tanh(aA[3] + aB[3]);
                float s4 = fast_tanh(bA[0] + bB[0]);
                float s5 = fast_tanh(bA[1] + bB[1]);
                float s6 = fast_tanh(bA[2] + bB[2]);
                float s7 = fast_tanh(bA[3] + bB[3]);

                pkg[g][0][pc].x = cvt_pk_bf16(s0, s1);
                pkg[g][0][pc].y = cvt_pk_bf16(s2, s3);
                pkg[g][1][pc].x = cvt_pk_bf16(s4, s5);
                pkg[g][1][pc].y = cvt_pk_bf16(s6, s7);

                *(uint2*)&st[g][pw][c][cw]      = pkg[g][0][pc];
                *(uint2*)&st[g][pw][c][cw + 16] = pkg[g][1][pc];
            }

            lds_barrier();
        }
        // advance bases by 8 rows (4096 B)
#pragma unroll
        for (int g = 0; g < 2; ++g) { pfb[g] += 4096; psb[g] += 4096; }
    }

    // epilogue: store st_{T-1} (computed at u=7 -> buffer 1); psb at row T
#pragma unroll
    for (int g = 0; g < 2; ++g) {
        *(uint2*)(psb[g] - 512)      = pkg[g][0][1];
        *(uint2*)(psb[g] - 512 + 32) = pkg[g][1][1];
    }
}

// ---------------------------------------------------------------------------
// Kernel 3: o[row][h] = tanh(st_row @ V + bv), in-place over out.
// ---------------------------------------------------------------------------
__global__ __launch_bounds__(256) void o_kernel(
    const float* __restrict__ st_in, float* __restrict__ o_out,
    const float* __restrict__ V, const float* __restrict__ bv)
{
    __shared__ bf16x8 vf[2048];
    const int tid  = threadIdx.x;
    const int lane = tid & 63;
    const int wave = tid >> 6;
    const int q = lane >> 4, c = lane & 15;

    for (int s = tid; s < 2048; s += 256) {
        int l = s & 63, kk = (s >> 6) & 3, nt = s >> 8;
        int lq = l >> 4, lc = l & 15;
        int kbase = 32 * kk + 8 * lq;
        int col = 16 * nt + lc;
        float v[8];
#pragma unroll
        for (int j = 0; j < 8; ++j) v[j] = V[(kbase + j) * H_ + col];
        union { bf16x8 v8; unsigned u[4]; } f;
#pragma unroll
        for (int j = 0; j < 4; ++j) f.u[j] = cvt_pk_bf16(v[2 * j], v[2 * j + 1]);
        vf[s] = f.v8;
    }

    f32x4 bias4[8];
#pragma unroll
    for (int nt = 0; nt < 8; ++nt)
        bias4[nt] = *(const f32x4*)(bv + 16 * nt + 4 * q);

    __syncthreads();

    for (int it = 0; it < 4; ++it) {
        const int row0 = (blockIdx.x * 4 + it) * 64 + wave * 16;
        const char* pa = (const char*)st_in + (size_t)(row0 + c) * (H_ * 4);
        bf16x8 af[4];
#pragma unroll
        for (int kk = 0; kk < 4; ++kk)
            af[kk] = *(const bf16x8*)(pa + 64 * kk + 16 * q);
        float* po = o_out + (size_t)(row0 + c) * H_ + 4 * q;
#pragma unroll
        for (int nt = 0; nt < 8; ++nt) {
            f32x4 acc = bias4[nt];
#pragma unroll
            for (int kk = 0; kk < 4; ++kk)
                acc = __builtin_amdgcn_mfma_f32_16x16x32_bf16(
                    vf[(nt * 4 + kk) * 64 + lane], af[kk], acc, 0, 0, 0);
            f32x4 o;
#pragma unroll
            for (int r = 0; r < 4; ++r) o[r] = fast_tanh(acc[r]);
            *(f32x4*)(po + 16 * nt) = o;
        }
    }
}

extern "C" void kernel_launch(void* const* d_in, const int* in_sizes, int n_in,
                              void* d_out, int out_size, void* d_ws, size_t ws_size,
                              hipStream_t stream) {
    const float* x  = (const float*)d_in[0];
    const float* h0 = (const float*)d_in[1];
    const float* U  = (const float*)d_in[2];
    const float* W  = (const float*)d_in[3];
    const float* V  = (const float*)d_in[4];
    const float* bu = (const float*)d_in[5];
    const float* bw = (const float*)d_in[6];
    const float* bv = (const float*)d_in[7];
    float* out = (float*)d_out;

    // xu = x@U + (bu+bw) into out[B*T][H] (f32)
    xu_kernel<<<512, 256, 0, stream>>>(x, U, bu, bw, out);
    // serial recurrence, 2 interleaved batch groups per block
    scan_kernel<<<4, 256, 0, stream>>>(out, out, h0, W);
    // o = tanh(st@V + bv), in-place over out (alias-split)
    o_kernel<<<512, 256, 0, stream>>>(out, out, V, bv);
}

// Round 6
// 825.920 us; speedup vs baseline: 1.5167x; 1.5167x over previous
//
#include <hip/hip_runtime.h>

#define B_ 128
#define T_ 1024
#define D_ 128
#define H_ 128

typedef short bf16x8 __attribute__((ext_vector_type(8)));
typedef float f32x4 __attribute__((ext_vector_type(4)));

// pack 2 f32 -> 2 bf16 (RNE) in one instruction (no builtin on gfx950)
__device__ inline unsigned cvt_pk_bf16(float lo, float hi) {
    unsigned r;
    asm("v_cvt_pk_bf16_f32 %0, %1, %2" : "=v"(r) : "v"(lo), "v"(hi));
    return r;
}

// tanh(x) = 1 - 2/(1+2^(x*2*log2(e))): mul, v_exp, add, rcp, fma
__device__ inline float fast_tanh(float x) {
    float e = __builtin_amdgcn_exp2f(x * 2.885390081777927f);
    float r = __builtin_amdgcn_rcpf(1.0f + e);
    return fmaf(-2.0f, r, 1.0f);
}

// lgkm-only barrier: keeps in-flight global loads/stores off the critical path
__device__ inline void lds_barrier() {
    asm volatile("s_waitcnt lgkmcnt(0)\n\ts_barrier" ::: "memory");
}

// ---------------------------------------------------------------------------
// Kernel 1: xu[rid = b*T + t][h] = x_row @ U + (bu + bw)  -> out (f32).
// ---------------------------------------------------------------------------
__global__ __launch_bounds__(256) void xu_kernel(
    const float* __restrict__ x, const float* __restrict__ U,
    const float* __restrict__ bu, const float* __restrict__ bw,
    float* __restrict__ out)
{
    __shared__ bf16x8 uf[2048];  // [nt(8)][kk(4)][lane(64)]: U[k][16nt+(l&15)]
    const int tid  = threadIdx.x;
    const int lane = tid & 63;
    const int wave = tid >> 6;
    const int q = lane >> 4, c = lane & 15;

    for (int s = tid; s < 2048; s += 256) {
        int l = s & 63, kk = (s >> 6) & 3, nt = s >> 8;
        int lq = l >> 4, lc = l & 15;
        int kbase = 32 * kk + 8 * lq;
        int col = 16 * nt + lc;
        float v[8];
#pragma unroll
        for (int j = 0; j < 8; ++j) v[j] = U[(kbase + j) * H_ + col];
        union { bf16x8 v8; unsigned u[4]; } f;
#pragma unroll
        for (int j = 0; j < 4; ++j) f.u[j] = cvt_pk_bf16(v[2 * j], v[2 * j + 1]);
        uf[s] = f.v8;
    }

    f32x4 bias4[8];
#pragma unroll
    for (int nt = 0; nt < 8; ++nt) {
        const int cb = 16 * nt + 4 * q;
        f32x4 a = *(const f32x4*)(bu + cb);
        f32x4 b = *(const f32x4*)(bw + cb);
#pragma unroll
        for (int r = 0; r < 4; ++r) bias4[nt][r] = a[r] + b[r];
    }

    __syncthreads();

    for (int it = 0; it < 4; ++it) {
        const int row0 = (blockIdx.x * 4 + it) * 64 + wave * 16;
        bf16x8 af[4];
#pragma unroll
        for (int kk = 0; kk < 4; ++kk) {
            const float* px = x + (size_t)(row0 + c) * D_ + 32 * kk + 8 * q;
            f32x4 a0 = *(const f32x4*)px;
            f32x4 a1 = *(const f32x4*)(px + 4);
            union { bf16x8 v8; unsigned u[4]; } f;
            f.u[0] = cvt_pk_bf16(a0[0], a0[1]);
            f.u[1] = cvt_pk_bf16(a0[2], a0[3]);
            f.u[2] = cvt_pk_bf16(a1[0], a1[1]);
            f.u[3] = cvt_pk_bf16(a1[2], a1[3]);
            af[kk] = f.v8;
        }
        float* po = out + (size_t)(row0 + c) * H_ + 4 * q;
#pragma unroll
        for (int nt = 0; nt < 8; ++nt) {
            f32x4 acc = bias4[nt];
#pragma unroll
            for (int kk = 0; kk < 4; ++kk)
                acc = __builtin_amdgcn_mfma_f32_16x16x32_bf16(
                    uf[(nt * 4 + kk) * 64 + lane], af[kk], acc, 0, 0, 0);
            *(f32x4*)(po + 16 * nt) = acc;
        }
    }
}

// ---------------------------------------------------------------------------
// Kernel 2: serial recurrence, R3 structure (8 blocks x 256 thr, 4 waves,
// 16 batch rows/block) with ALL GLOBAL OPS EVICTED from the per-step window:
//  - xu loads batched: 16 loads per 8-step window, issued at window start
//    into the inactive one of two NAMED register buffers (no dyn indexing).
//  - st stores batched: 8 steps of packed bf16 accumulate in regs (pks),
//    burst-stored after the window's final barrier.
// Per step the vmcnt stream is EMPTY -> no in-order-retire entanglement of
// xu-load waits behind HBM store completion. Race safety: loads of rows
// t..t+7 are consumed (waitcnt'd) during window t/8; the end-of-window
// barrier orders all waves' consumption before any wave's store burst.
// ---------------------------------------------------------------------------
__device__ __forceinline__ void scan_window(
    f32x4 (&cur)[8][2], f32x4 (&nxt)[8][2],
    const float*& pf, char*& pst, int& tbase,
    short (&st)[2][16][136], const bf16x8 (&wf)[2][4],
    int c, int q, int cw)
{
    // (1) issue next window's 16 xu loads (planes tbase+8 .. tbase+15)
    if (tbase + 16 <= T_) {
#pragma unroll
        for (int u = 0; u < 8; ++u) {
            nxt[u][0] = *(const f32x4*)(pf + u * H_);
            nxt[u][1] = *(const f32x4*)(pf + u * H_ + 16);
        }
        pf += 8 * H_;
    }

    const f32x4 z4 = {0.f, 0.f, 0.f, 0.f};
    uint2 pks[8][2];

    // (2) 8 serial steps, LDS-only
#pragma unroll
    for (int u = 0; u < 8; ++u) {
        const int pr = (u + 1) & 1;  // slot holding st_{t-1}
        const int pw = u & 1;        // slot to write st_t

        bf16x8 af[4];
#pragma unroll
        for (int kk = 0; kk < 4; ++kk)
            af[kk] = *(const bf16x8*)&st[pr][c][32 * kk + 8 * q];

        f32x4 aA = __builtin_amdgcn_mfma_f32_16x16x32_bf16(wf[0][0], af[0], cur[u][0], 0, 0, 0);
        f32x4 aB = __builtin_amdgcn_mfma_f32_16x16x32_bf16(wf[0][1], af[1], z4,        0, 0, 0);
        f32x4 bA = __builtin_amdgcn_mfma_f32_16x16x32_bf16(wf[1][0], af[0], cur[u][1], 0, 0, 0);
        f32x4 bB = __builtin_amdgcn_mfma_f32_16x16x32_bf16(wf[1][1], af[1], z4,        0, 0, 0);
        aA = __builtin_amdgcn_mfma_f32_16x16x32_bf16(wf[0][2], af[2], aA, 0, 0, 0);
        aB = __builtin_amdgcn_mfma_f32_16x16x32_bf16(wf[0][3], af[3], aB, 0, 0, 0);
        bA = __builtin_amdgcn_mfma_f32_16x16x32_bf16(wf[1][2], af[2], bA, 0, 0, 0);
        bB = __builtin_amdgcn_mfma_f32_16x16x32_bf16(wf[1][3], af[3], bB, 0, 0, 0);

        float s0 = fast_tanh(aA[0] + aB[0]);
        float s1 = fast_tanh(aA[1] + aB[1]);
        float s2 = fast_tanh(aA[2] + aB[2]);
        float s3 = fast_tanh(aA[3] + aB[3]);
        float s4 = fast_tanh(bA[0] + bB[0]);
        float s5 = fast_tanh(bA[1] + bB[1]);
        float s6 = fast_tanh(bA[2] + bB[2]);
        float s7 = fast_tanh(bA[3] + bB[3]);

        pks[u][0].x = cvt_pk_bf16(s0, s1);
        pks[u][0].y = cvt_pk_bf16(s2, s3);
        pks[u][1].x = cvt_pk_bf16(s4, s5);
        pks[u][1].y = cvt_pk_bf16(s6, s7);

        *(uint2*)&st[pw][c][cw]      = pks[u][0];  // ds_write_b64, packed
        *(uint2*)&st[pw][c][cw + 16] = pks[u][1];

        lds_barrier();
    }

    // (3) burst-store this window's st rows (tbase .. tbase+7), bf16 packed
#pragma unroll
    for (int u = 0; u < 8; ++u) {
        *(uint2*)(pst + u * 512)      = pks[u][0];
        *(uint2*)(pst + u * 512 + 32) = pks[u][1];
    }
    pst += 4096;
    tbase += 8;
}

__global__ __launch_bounds__(256, 1) void scan_kernel(
    const float* __restrict__ xu_in, float* __restrict__ st_out,
    const float* __restrict__ h0, const float* __restrict__ W)
{
    // st slots: [parity][m=16][k=128 + 8 pad] bf16 (272B row stride)
    __shared__ __align__(16) short st[2][16][136];

    const int tid  = threadIdx.x;
    const int lane = tid & 63;
    const int wave = tid >> 6;           // 0..3
    const int q = lane >> 4, c = lane & 15;
    const int b0 = blockIdx.x * 16;
    const int cw = wave * 32 + 4 * q;    // per-lane col base (tile 0)

    // A-frags of W^T (regs, all steps): A[i=lane&15][k] = W[k][c0+i]
    bf16x8 wf[2][4];
#pragma unroll
    for (int tt = 0; tt < 2; ++tt) {
        const int c0 = wave * 32 + tt * 16;
#pragma unroll
        for (int kk = 0; kk < 4; ++kk) {
            const int kbase = 32 * kk + 8 * q;
            float v[8];
#pragma unroll
            for (int j = 0; j < 8; ++j) v[j] = W[(kbase + j) * H_ + c0 + c];
            union { bf16x8 v8; unsigned u[4]; } f;
#pragma unroll
            for (int j = 0; j < 4; ++j) f.u[j] = cvt_pk_bf16(v[2 * j], v[2 * j + 1]);
            wf[tt][kk] = f.v8;
        }
    }

    // stage h0 -> slot[1] (st_{-1}); 256 thr x 8 shorts, packed b128 writes
    {
        const int m = tid >> 4, k0 = (tid & 15) * 8;
        const float* ph = h0 + (size_t)(b0 + m) * H_ + k0;
        f32x4 a0 = *(const f32x4*)ph;
        f32x4 a1 = *(const f32x4*)(ph + 4);
        union { bf16x8 v8; unsigned u[4]; } f;
        f.u[0] = cvt_pk_bf16(a0[0], a0[1]);
        f.u[1] = cvt_pk_bf16(a0[2], a0[3]);
        f.u[2] = cvt_pk_bf16(a1[0], a1[1]);
        f.u[3] = cvt_pk_bf16(a1[2], a1[3]);
        *(bf16x8*)&st[1][m][k0] = f.v8;
    }

    // two NAMED xu window buffers (8 planes x 2 f32x4 each); prologue fills A
    const float* xup = xu_in + ((size_t)(b0 + c) * T_) * H_ + cw;
    f32x4 xbA[8][2], xbB[8][2];
#pragma unroll
    for (int u = 0; u < 8; ++u) {
        xbA[u][0] = *(const f32x4*)(xup + u * H_);
        xbA[u][1] = *(const f32x4*)(xup + u * H_ + 16);
    }
    const float* pf = xup + 8 * H_;
    char* pst = (char*)st_out + ((size_t)(b0 + c) * T_) * H_ * 4 + cw * 2;
    int tbase = 0;

    lds_barrier();

    for (int it2 = 0; it2 < T_ / 16; ++it2) {
        scan_window(xbA, xbB, pf, pst, tbase, st, wf, c, q, cw);
        scan_window(xbB, xbA, pf, pst, tbase, st, wf, c, q, cw);
    }
}

// ---------------------------------------------------------------------------
// Kernel 3: o[row][h] = tanh(st_row @ V + bv), in-place over out.
// ---------------------------------------------------------------------------
__global__ __launch_bounds__(256) void o_kernel(
    const float* __restrict__ st_in, float* __restrict__ o_out,
    const float* __restrict__ V, const float* __restrict__ bv)
{
    __shared__ bf16x8 vf[2048];
    const int tid  = threadIdx.x;
    const int lane = tid & 63;
    const int wave = tid >> 6;
    const int q = lane >> 4, c = lane & 15;

    for (int s = tid; s < 2048; s += 256) {
        int l = s & 63, kk = (s >> 6) & 3, nt = s >> 8;
        int lq = l >> 4, lc = l & 15;
        int kbase = 32 * kk + 8 * lq;
        int col = 16 * nt + lc;
        float v[8];
#pragma unroll
        for (int j = 0; j < 8; ++j) v[j] = V[(kbase + j) * H_ + col];
        union { bf16x8 v8; unsigned u[4]; } f;
#pragma unroll
        for (int j = 0; j < 4; ++j) f.u[j] = cvt_pk_bf16(v[2 * j], v[2 * j + 1]);
        vf[s] = f.v8;
    }

    f32x4 bias4[8];
#pragma unroll
    for (int nt = 0; nt < 8; ++nt)
        bias4[nt] = *(const f32x4*)(bv + 16 * nt + 4 * q);

    __syncthreads();

    for (int it = 0; it < 4; ++it) {
        const int row0 = (blockIdx.x * 4 + it) * 64 + wave * 16;
        const char* pa = (const char*)st_in + (size_t)(row0 + c) * (H_ * 4);
        bf16x8 af[4];
#pragma unroll
        for (int kk = 0; kk < 4; ++kk)
            af[kk] = *(const bf16x8*)(pa + 64 * kk + 16 * q);
        float* po = o_out + (size_t)(row0 + c) * H_ + 4 * q;
#pragma unroll
        for (int nt = 0; nt < 8; ++nt) {
            f32x4 acc = bias4[nt];
#pragma unroll
            for (int kk = 0; kk < 4; ++kk)
                acc = __builtin_amdgcn_mfma_f32_16x16x32_bf16(
                    vf[(nt * 4 + kk) * 64 + lane], af[kk], acc, 0, 0, 0);
            f32x4 o;
#pragma unroll
            for (int r = 0; r < 4; ++r) o[r] = fast_tanh(acc[r]);
            *(f32x4*)(po + 16 * nt) = o;
        }
    }
}

extern "C" void kernel_launch(void* const* d_in, const int* in_sizes, int n_in,
                              void* d_out, int out_size, void* d_ws, size_t ws_size,
                              hipStream_t stream) {
    const float* x  = (const float*)d_in[0];
    const float* h0 = (const float*)d_in[1];
    const float* U  = (const float*)d_in[2];
    const float* W  = (const float*)d_in[3];
    const float* V  = (const float*)d_in[4];
    const float* bu = (const float*)d_in[5];
    const float* bw = (const float*)d_in[6];
    const float* bv = (const float*)d_in[7];
    float* out = (float*)d_out;

    // xu = x@U + (bu+bw) into out[B*T][H] (f32)
    xu_kernel<<<512, 256, 0, stream>>>(x, U, bu, bw, out);
    // serial recurrence; batched global I/O per 8-step window
    scan_kernel<<<8, 256, 0, stream>>>(out, out, h0, W);
    // o = tanh(st@V + bv), in-place over out (alias-split)
    o_kernel<<<512, 256, 0, stream>>>(out, out, V, bv);
}